// Round 9
// baseline (667.300 us; speedup 1.0000x reference)
//
#include <hip/hip_runtime.h>
#include <hip/hip_bf16.h>

// ---------------------------------------------------------------------------
// MultiHeadSelfAttention: B=4, L=2048, D=1024, H=16, dh=64.
// Conventions (proven R6): inputs fp32, mask int32, d_out fp32 storage.
// R9: attention computes S^T = K*Q^T so the softmax C-frag is ALREADY the
// B-operand layout of the K=16 PV MFMA (O^T = V^T * P^T): no LDS, no barrier,
// no layout transform. x pre-converted to bf16 once; packed bf16 cvt staging.
// ---------------------------------------------------------------------------

typedef __attribute__((ext_vector_type(8))) short short8;   // 8 bf16
typedef __attribute__((ext_vector_type(4))) short short4v;  // 4 bf16
typedef __attribute__((ext_vector_type(4))) float f32x4;
typedef __attribute__((ext_vector_type(4))) unsigned u32x4;

#define MFMA_K32(a, b, c) __builtin_amdgcn_mfma_f32_16x16x32_bf16((a), (b), (c), 0, 0, 0)
#define MFMA_K16(a, b, c) __builtin_amdgcn_mfma_f32_16x16x16bf16_1k((a), (b), (c), 0, 0, 0)

__device__ __forceinline__ unsigned pk2(float a, float b) {
    __hip_bfloat162 h = __float22bfloat162_rn(make_float2(a, b));  // RNE
    unsigned u; __builtin_memcpy(&u, &h, 4); return u;
}

// ---------------------------------------------------------------------------
// x (fp32, 8M elems) -> bf16, staged into d_out (dead until attn writes O).
// ---------------------------------------------------------------------------
__global__ __launch_bounds__(256) void convert_x(const float* __restrict__ x,
                                                 short* __restrict__ xb)
{
    const size_t i = ((size_t)blockIdx.x * 256 + threadIdx.x) * 8;
    f32x4 a = *(const f32x4*)(x + i);
    f32x4 b = *(const f32x4*)(x + i + 4);
    u32x4 o;
    o[0] = pk2(a[0], a[1]); o[1] = pk2(a[2], a[3]);
    o[2] = pk2(b[0], b[1]); o[3] = pk2(b[2], b[3]);
    *(u32x4*)(xb + i) = o;
}

// ---------------------------------------------------------------------------
// GEMM: out = A(8192 x 1024) * W^T + bias. W,bias fp32 (torch Linear (N,K)).
// AF=1: A fp32 (packed-cvt staging); AF=0: A bf16.
// layout 0 -> bf16 (B,H,L,dh); 2 -> bf16 (B,H,dh,L); 3 -> fp32 (M,1024).
// ---------------------------------------------------------------------------
template <int AF>
__global__ __launch_bounds__(256, 2) void gemm_kernel(
    const void* __restrict__ Ap, const float* __restrict__ W,
    const float* __restrict__ bias, void* __restrict__ out, int layout)
{
    __shared__ short As[128 * 40];
    __shared__ short Bs[128 * 40];

    const int m0 = blockIdx.x * 128;
    const int n0 = blockIdx.y * 128;
    const int t = threadIdx.x;
    const int wave = t >> 6, lane = t & 63;
    const int wm = (wave >> 1) * 64, wn = (wave & 1) * 64;
    const int l15 = lane & 15, quad = lane >> 4;
    const int srow = t >> 2;          // 0..63
    const int scol = (t & 3) * 8;     // 0,8,16,24

    f32x4 acc[4][4];
#pragma unroll
    for (int i = 0; i < 4; i++)
#pragma unroll
        for (int j = 0; j < 4; j++) {
            acc[i][j][0] = 0.f; acc[i][j][1] = 0.f;
            acc[i][j][2] = 0.f; acc[i][j][3] = 0.f;
        }

    const size_t aoff0 = (size_t)(m0 + srow) * 1024 + scol;
    const size_t aoff1 = aoff0 + (size_t)64 * 1024;
    const size_t woff0 = (size_t)(n0 + srow) * 1024 + scol;
    const size_t woff1 = woff0 + (size_t)64 * 1024;

    for (int kb = 0; kb < 1024; kb += 32) {
        __syncthreads();
        if (AF) {
            const float* Af = (const float*)Ap;
#pragma unroll
            for (int half = 0; half < 2; half++) {
                const float* p = Af + (half ? aoff1 : aoff0) + kb;
                f32x4 u0 = *(const f32x4*)p;
                f32x4 u1 = *(const f32x4*)(p + 4);
                u32x4 s;
                s[0] = pk2(u0[0], u0[1]); s[1] = pk2(u0[2], u0[3]);
                s[2] = pk2(u1[0], u1[1]); s[3] = pk2(u1[2], u1[3]);
                *(u32x4*)&As[(srow + half * 64) * 40 + scol] = s;
            }
        } else {
            const short* Ab = (const short*)Ap;
            *(short8*)&As[srow * 40 + scol]        = *(const short8*)(Ab + aoff0 + kb);
            *(short8*)&As[(srow + 64) * 40 + scol] = *(const short8*)(Ab + aoff1 + kb);
        }
#pragma unroll
        for (int half = 0; half < 2; half++) {
            const float* p = W + (half ? woff1 : woff0) + kb;
            f32x4 u0 = *(const f32x4*)p;
            f32x4 u1 = *(const f32x4*)(p + 4);
            u32x4 s;
            s[0] = pk2(u0[0], u0[1]); s[1] = pk2(u0[2], u0[3]);
            s[2] = pk2(u1[0], u1[1]); s[3] = pk2(u1[2], u1[3]);
            *(u32x4*)&Bs[(srow + half * 64) * 40 + scol] = s;
        }
        __syncthreads();

        short8 af[4], bfr[4];
#pragma unroll
        for (int mi = 0; mi < 4; mi++)
            af[mi] = *(short8*)&As[(wm + mi * 16 + l15) * 40 + quad * 8];
#pragma unroll
        for (int ni = 0; ni < 4; ni++)
            bfr[ni] = *(short8*)&Bs[(wn + ni * 16 + l15) * 40 + quad * 8];
#pragma unroll
        for (int mi = 0; mi < 4; mi++)
#pragma unroll
            for (int ni = 0; ni < 4; ni++)
                acc[mi][ni] = MFMA_K32(af[mi], bfr[ni], acc[mi][ni]);
    }

    // Epilogue. C layout: col = lane&15, row = quad*4 + r.
#pragma unroll
    for (int ni = 0; ni < 4; ni++) {
        const int gn = n0 + wn + ni * 16 + l15;
        const float bv = bias[gn];
#pragma unroll
        for (int mi = 0; mi < 4; mi++) {
#pragma unroll
            for (int r = 0; r < 4; r++) {
                const int gm = m0 + wm + mi * 16 + quad * 4 + r;
                const float v = acc[mi][ni][r] + bv;
                if (layout == 3) {
                    ((float*)out)[(size_t)gm * 1024 + gn] = v;
                } else {
                    const int b = gm >> 11, l = gm & 2047;  // L = 2048
                    const int h = gn >> 6,  d = gn & 63;    // dh = 64
                    size_t idx;
                    if (layout == 2)
                        idx = ((size_t)(b * 16 + h) * 64 + d) * 2048 + l;
                    else
                        idx = ((size_t)(b * 16 + h) * 2048 + l) * 64 + d;
                    ((short*)out)[idx] = (short)(pk2(v, 0.f) & 0xFFFF);
                }
            }
        }
    }
}

// ---------------------------------------------------------------------------
// Attention (static-max softmax, proven exact at 2.44e-4). Block = 4 waves x
// 2 q-tiles (32 rows/wave); 64-key chunks. S^T = K*Q^T via K=32 MFMA: C-frag
// lane holds (q = lane&15, key = quad*4+r) == B-operand layout of K=16 MFMA.
// PV: O^T = V^T * P^T with A = V^T (contiguous from VT). No LDS at all.
// XCD-affine: bh = blk & 63. Q,K bf16 (B,H,L,dh); VT bf16 (B,H,dh,L);
// mask int32; O fp32 (B,L,D).
// ---------------------------------------------------------------------------
__global__ __launch_bounds__(256, 3) void attn_kernel(
    const short* __restrict__ Q, const short* __restrict__ Kc,
    const short* __restrict__ VT, const int* __restrict__ mask,
    float* __restrict__ O)
{
    const int blk = blockIdx.x;          // 1024 blocks
    const int bh = blk & 63;             // same bh -> same XCD
    const int qg = blk >> 6;             // 0..15 (128 rows each)
    const int b = bh >> 4, h = bh & 15;
    const int t = threadIdx.x;
    const int wave = t >> 6, lane = t & 63;
    const int l15 = lane & 15, quad = lane >> 4;

    const short* Qb = Q  + (size_t)bh * 2048 * 64;
    const short* Kb = Kc + (size_t)bh * 2048 * 64;
    const short* Vb = VT + (size_t)bh * 64 * 2048;
    const int* mrow = mask + b * 2048;

    const float SC = 0.125f * 1.44269504f;  // 1/sqrt(dh) folded into exp2

    const int qbase = qg * 128 + wave * 32;

    // Q fragments, used as B-operand (n = lane&15 = q, k = quad*8+j = dh).
    short8 bq[2][2];
#pragma unroll
    for (int tt = 0; tt < 2; tt++) {
        const short* qp = Qb + (size_t)(qbase + tt * 16 + l15) * 64 + quad * 8;
        bq[tt][0] = *(const short8*)(qp);
        bq[tt][1] = *(const short8*)(qp + 32);
    }

    f32x4 accOT[2][4];   // [q-tile][d-tile]: O^T frag (d = quad*4+r, q = l15)
#pragma unroll
    for (int tt = 0; tt < 2; tt++)
#pragma unroll
        for (int dt = 0; dt < 4; dt++) {
            accOT[tt][dt][0] = 0.f; accOT[tt][dt][1] = 0.f;
            accOT[tt][dt][2] = 0.f; accOT[tt][dt][3] = 0.f;
        }
    float lsum[2] = {0.f, 0.f};   // per-lane partial row sum (q = l15)

    for (int c0 = 0; c0 < 2048; c0 += 64) {
        // --- K fragments, used as A-operand (m = l15 = key, k = dh) ---
        short8 ka[4][2];
#pragma unroll
        for (int g = 0; g < 4; g++) {
            const short* kp = Kb + (size_t)(c0 + g * 16 + l15) * 64 + quad * 8;
            ka[g][0] = *(const short8*)(kp);
            ka[g][1] = *(const short8*)(kp + 32);
        }
        // --- mask: key = c0 + g*16 + quad*4 + r ---
        int4 mv[4];
#pragma unroll
        for (int g = 0; g < 4; g++)
            mv[g] = *(const int4*)(mrow + c0 + g * 16 + quad * 4);

        // --- S^T = K * Q^T (C-frag: q = l15, key = quad*4+r) ---
        f32x4 s[2][4];
#pragma unroll
        for (int tt = 0; tt < 2; tt++)
#pragma unroll
            for (int g = 0; g < 4; g++) {
                f32x4 z; z[0]=0.f; z[1]=0.f; z[2]=0.f; z[3]=0.f;
                z = MFMA_K32(ka[g][0], bq[tt][0], z);
                s[tt][g] = MFMA_K32(ka[g][1], bq[tt][1], z);
            }

        // --- V^T fragments for PV (A-operand: m = l15 = d, k = quad*4+j) ---
        short4v vt[4][4];
#pragma unroll
        for (int dt = 0; dt < 4; dt++)
#pragma unroll
            for (int g = 0; g < 4; g++)
                vt[dt][g] = *(const short4v*)(Vb + (size_t)(dt * 16 + l15) * 2048
                                              + c0 + g * 16 + quad * 4);

        // --- P = exp2(S^T * SC) masked, packed bf16; accumulate row sums ---
        short4v pf[2][4];
#pragma unroll
        for (int tt = 0; tt < 2; tt++)
#pragma unroll
            for (int g = 0; g < 4; g++) {
                const float p0 = mv[g].x ? 0.f : exp2f(s[tt][g][0] * SC);
                const float p1 = mv[g].y ? 0.f : exp2f(s[tt][g][1] * SC);
                const float p2 = mv[g].z ? 0.f : exp2f(s[tt][g][2] * SC);
                const float p3 = mv[g].w ? 0.f : exp2f(s[tt][g][3] * SC);
                lsum[tt] += (p0 + p1) + (p2 + p3);
                union { short4v s4; unsigned u[2]; } pu;
                pu.u[0] = pk2(p0, p1);
                pu.u[1] = pk2(p2, p3);
                pf[tt][g] = pu.s4;
            }

        // --- O^T += V^T * P^T (K=16 MFMAs, no transform needed) ---
#pragma unroll
        for (int tt = 0; tt < 2; tt++)
#pragma unroll
            for (int g = 0; g < 4; g++)
#pragma unroll
                for (int dt = 0; dt < 4; dt++)
                    accOT[tt][dt] = MFMA_K16(vt[dt][g], pf[tt][g], accOT[tt][dt]);
    }

    // Epilogue: reduce lsum across quads (same q = l15), normalize, store.
#pragma unroll
    for (int tt = 0; tt < 2; tt++) {
        float ls = lsum[tt];
        ls += __shfl_xor(ls, 16);
        ls += __shfl_xor(ls, 32);
        const float inv = 1.0f / fmaxf(ls, 1e-30f);
        const int l = qbase + tt * 16 + l15;
        float* op = O + (size_t)(b * 2048 + l) * 1024 + h * 64 + quad * 4;
#pragma unroll
        for (int dt = 0; dt < 4; dt++) {
            f32x4 o;
            o[0] = accOT[tt][dt][0] * inv; o[1] = accOT[tt][dt][1] * inv;
            o[2] = accOT[tt][dt][2] * inv; o[3] = accOT[tt][dt][3] * inv;
            *(f32x4*)(op + dt * 16) = o;
        }
    }
}

// ---------------------------------------------------------------------------
extern "C" void kernel_launch(void* const* d_in, const int* in_sizes, int n_in,
                              void* d_out, int out_size, void* d_ws, size_t ws_size,
                              hipStream_t stream)
{
    const float* x    = (const float*)d_in[0];
    const int*   mask = (const int*)d_in[1];
    const float* wq   = (const float*)d_in[2];
    const float* bq   = (const float*)d_in[3];
    const float* wk   = (const float*)d_in[4];
    const float* bk   = (const float*)d_in[5];
    const float* wv   = (const float*)d_in[6];
    const float* bv   = (const float*)d_in[7];
    const float* wo   = (const float*)d_in[8];
    const float* bo   = (const float*)d_in[9];
    float* out = (float*)d_out;   // fp32 output (8M floats, 32 MB)

    // ws (48 MiB): [Qbuf bf16 16MB][Kbuf bf16 16MB][Vt bf16 16MB]
    short* Qbuf = (short*)d_ws;
    short* Kbuf = Qbuf + (size_t)8 * 1024 * 1024;
    short* Vt   = Kbuf + (size_t)8 * 1024 * 1024;
    float* Fout = (float*)d_ws;       // final GEMM result over Qbuf+Kbuf (dead)
    short* xbf  = (short*)d_out;      // bf16 x staged in d_out (dead until attn)

    dim3 block(256);
    convert_x<<<dim3(4096), block, 0, stream>>>(x, xbf);

    dim3 grid(64, 8);
    gemm_kernel<0><<<grid, block, 0, stream>>>(xbf, wq, bq, Qbuf, 0);
    gemm_kernel<0><<<grid, block, 0, stream>>>(xbf, wk, bk, Kbuf, 0);
    gemm_kernel<0><<<grid, block, 0, stream>>>(xbf, wv, bv, Vt, 2);

    attn_kernel<<<dim3(1024), block, 0, stream>>>(Qbuf, Kbuf, Vt, mask, out);

    gemm_kernel<1><<<grid, block, 0, stream>>>(out, wo, bo, Fout, 3);

    hipMemcpyAsync(out, Fout, (size_t)out_size * sizeof(float),
                   hipMemcpyDeviceToDevice, stream);
}